// Round 5
// baseline (229.993 us; speedup 1.0000x reference)
//
#include <hip/hip_runtime.h>

#define HH 1024
#define WW 1024
#define NB 8
#define TY 16
#define BANDS 4                              // 4 bands x 256 cols
#define NCC_WAVES (NB * BANDS * (HH / TY))   // 2048
#define NCC_BLOCKS (NCC_WAVES / 4)           // 512
#define SM_BLOCKS 256                        // 1024 SM waves x 16 rows
#define GRID (NCC_BLOCKS + SM_BLOCKS)        // 768
#define RW (1.0f / 81.0f)

template <int SGN>
__device__ __forceinline__ void acc4(const float4 a, const float4 b,
                                     float vI[4], float vJ[4],
                                     float vI2[4], float vJ2[4], float vIJ[4]) {
    const float fa[4] = {a.x, a.y, a.z, a.w};
    const float fb[4] = {b.x, b.y, b.z, b.w};
#pragma unroll
    for (int c = 0; c < 4; ++c) {
        const float x = fa[c], y = fb[c];
        if (SGN > 0) {
            vI[c] += x; vJ[c] += y;
            vI2[c] = fmaf(x, x, vI2[c]);
            vJ2[c] = fmaf(y, y, vJ2[c]);
            vIJ[c] = fmaf(x, y, vIJ[c]);
        } else {
            vI[c] -= x; vJ[c] -= y;
            vI2[c] = fmaf(-x, x, vI2[c]);
            vJ2[c] = fmaf(-y, y, vJ2[c]);
            vIJ[c] = fmaf(-x, y, vIJ[c]);
        }
    }
}

// 9-wide horizontal windows over column sums for this lane's 4 output columns.
// h[] is the self-maintained halo column-sum (zeros unless this lane is a band
// edge with a live neighbor band), so no band-conditionals are needed here.
__device__ __forceinline__ void slide(int lane, const float v[4], const float h[4], float W[4]) {
    float l0 = __shfl_up(v[0], 1), l1 = __shfl_up(v[1], 1);
    float l2 = __shfl_up(v[2], 1), l3 = __shfl_up(v[3], 1);
    float r0 = __shfl_down(v[0], 1), r1 = __shfl_down(v[1], 1);
    float r2 = __shfl_down(v[2], 1), r3 = __shfl_down(v[3], 1);
    if (lane == 0) { l0 = h[0]; l1 = h[1]; l2 = h[2]; l3 = h[3]; }
    if (lane == 63) { r0 = h[0]; r1 = h[1]; r2 = h[2]; r3 = h[3]; }
    float w = l0 + l1 + l2 + l3 + v[0] + v[1] + v[2] + v[3] + r0;
    W[0] = w;
    w += r1 - l0; W[1] = w;
    w += r2 - l1; W[2] = w;
    w += r3 - l2; W[3] = w;
}

__global__ __launch_bounds__(256, 4) void fused_kernel(const float* __restrict__ I,
                                                       const float* __restrict__ J,
                                                       const float* __restrict__ S,
                                                       float* __restrict__ ws) {
    __shared__ float red[8];
    const int bid = blockIdx.x;
    const int t = threadIdx.x;
    const int lane = t & 63;
    const int wid = t >> 6;

    if ((bid % 3) < 2) {
        // ------------- NCC: wave = 256-col band x TY rows, fully autonomous -------------
        const int nblk = (bid / 3) * 2 + (bid % 3);   // [0, 512)
        const int ss = nblk * 4 + wid;                // [0, 2048)
        const int b = ss >> 8;                        // image
        const int rem = ss & 255;
        const int band = rem & 3;
        const int y0 = (rem >> 2) * TY;
        const int x0 = band * 256 + lane * 4;
        const float* Ib = I + (size_t)b * HH * WW;
        const float* Jb = J + (size_t)b * HH * WW;

        const bool haloL = (lane == 0) && (band > 0);
        const bool haloR = (lane == 63) && (band < BANDS - 1);
        const bool halo = haloL || haloR;
        const int hx = x0 + (haloL ? -4 : 4);

        float vI[4] = {0, 0, 0, 0}, vJ[4] = {0, 0, 0, 0};
        float vI2[4] = {0, 0, 0, 0}, vJ2[4] = {0, 0, 0, 0}, vIJ[4] = {0, 0, 0, 0};
        float hI[4] = {0, 0, 0, 0}, hJ[4] = {0, 0, 0, 0};
        float hI2[4] = {0, 0, 0, 0}, hJ2[4] = {0, 0, 0, 0}, hIJ[4] = {0, 0, 0, 0};
        float ccacc = 0.f;

        // warm-up: rows y0-4 .. y0+3 (add only)
#pragma unroll 2
        for (int k = 0; k < 8; ++k) {
            const int y = y0 - 4 + k;
            if (y < 0) continue;                       // wave-uniform
            const float* rowI = Ib + (size_t)y * WW;
            const float* rowJ = Jb + (size_t)y * WW;
            const float4 a = *(const float4*)(rowI + x0);
            const float4 bb = *(const float4*)(rowJ + x0);
            float4 ha{0, 0, 0, 0}, hb{0, 0, 0, 0};
            if (halo) { ha = *(const float4*)(rowI + hx); hb = *(const float4*)(rowJ + hx); }
            acc4<1>(a, bb, vI, vJ, vI2, vJ2, vIJ);
            acc4<1>(ha, hb, hI, hJ, hI2, hJ2, hIJ);
        }

#pragma unroll 2
        for (int k = 0; k < TY; ++k) {
            const int y = y0 + k;
            const int ya = y + 4, ys = y - 4;
            const bool la = (ya < HH), ls = (ys >= 0);  // wave-uniform

            // issue add-row AND sub-row loads together (8+ independent loads)
            float4 aI{0, 0, 0, 0}, aJ{0, 0, 0, 0}, haI{0, 0, 0, 0}, haJ{0, 0, 0, 0};
            float4 sI{0, 0, 0, 0}, sJ{0, 0, 0, 0}, hsI{0, 0, 0, 0}, hsJ{0, 0, 0, 0};
            if (la) {
                const float* rowI = Ib + (size_t)ya * WW;
                const float* rowJ = Jb + (size_t)ya * WW;
                aI = *(const float4*)(rowI + x0);
                aJ = *(const float4*)(rowJ + x0);
                if (halo) { haI = *(const float4*)(rowI + hx); haJ = *(const float4*)(rowJ + hx); }
            }
            if (ls) {
                const float* rowI = Ib + (size_t)ys * WW;
                const float* rowJ = Jb + (size_t)ys * WW;
                sI = *(const float4*)(rowI + x0);
                sJ = *(const float4*)(rowJ + x0);
                if (halo) { hsI = *(const float4*)(rowI + hx); hsJ = *(const float4*)(rowJ + hx); }
            }

            acc4<1>(aI, aJ, vI, vJ, vI2, vJ2, vIJ);
            acc4<1>(haI, haJ, hI, hJ, hI2, hJ2, hIJ);

            // windows per quantity (temps die per slide call)
            float W0[4], W1[4], W2[4], W3[4], W4[4];
            slide(lane, vI, hI, W0);
            slide(lane, vJ, hJ, W1);
            slide(lane, vI2, hI2, W2);
            slide(lane, vJ2, hJ2, W3);
            slide(lane, vIJ, hIJ, W4);

#pragma unroll
            for (int c = 0; c < 4; ++c) {
                const float Is = W0[c], Js = W1[c];
                const float cross = fmaf(-Is * Js, RW, W4[c]);
                const float Iv = fmaf(-Is * Is, RW, W2[c]);
                const float Jv = fmaf(-Js * Js, RW, W3[c]);
                const float den = fmaf(Iv, Jv, 1e-9f);
                ccacc += cross * cross * __builtin_amdgcn_rcpf(den);
            }

            acc4<-1>(sI, sJ, vI, vJ, vI2, vJ2, vIJ);
            acc4<-1>(hsI, hsJ, hI, hJ, hI2, hJ2, hIJ);
        }

#pragma unroll
        for (int o = 32; o; o >>= 1) ccacc += __shfl_down(ccacc, o);
        if (lane == 0) red[wid] = ccacc;
        __syncthreads();
        if (t == 0) ws[nblk] = red[0] + red[1] + red[2] + red[3];
    } else {
        // ------------- smoothness: wave = 16 rows x 1024 cols -------------
        const int sb = bid / 3;                        // [0, 256)
        const int r0 = sb * 64 + wid * 16;             // flat row [0, 16384)
        const float* base = S + (size_t)r0 * WW;
        float dxacc = 0.f, dyacc = 0.f;

        float4 v[4];
        {
            const float4* rp4 = (const float4*)base + 4 * lane;
#pragma unroll
            for (int k = 0; k < 4; ++k) v[k] = rp4[k];
        }
#pragma unroll 2
        for (int k = 0; k < 16; ++k) {
            const float f[16] = {v[0].x, v[0].y, v[0].z, v[0].w, v[1].x, v[1].y, v[1].z, v[1].w,
                                 v[2].x, v[2].y, v[2].z, v[2].w, v[3].x, v[3].y, v[3].z, v[3].w};
#pragma unroll
            for (int c = 0; c < 15; ++c) { const float d = f[c + 1] - f[c]; dxacc = fmaf(d, d, dxacc); }
            const float nb0 = __shfl_down(v[0].x, 1);
            if (lane < 63) { const float d = nb0 - f[15]; dxacc = fmaf(d, d, dxacc); }

            if (((r0 + k) & (HH - 1)) != HH - 1) {
                const float4* np4 = (const float4*)(base + (size_t)(k + 1) * WW) + 4 * lane;
                float4 nv[4];
#pragma unroll
                for (int q = 0; q < 4; ++q) nv[q] = np4[q];
#pragma unroll
                for (int q = 0; q < 4; ++q) {
                    const float e0 = nv[q].x - v[q].x, e1 = nv[q].y - v[q].y;
                    const float e2 = nv[q].z - v[q].z, e3 = nv[q].w - v[q].w;
                    dyacc = fmaf(e0, e0, dyacc); dyacc = fmaf(e1, e1, dyacc);
                    dyacc = fmaf(e2, e2, dyacc); dyacc = fmaf(e3, e3, dyacc);
                }
#pragma unroll
                for (int q = 0; q < 4; ++q) v[q] = nv[q];
            }
        }

#pragma unroll
        for (int o = 32; o; o >>= 1) {
            dxacc += __shfl_down(dxacc, o);
            dyacc += __shfl_down(dyacc, o);
        }
        if (lane == 0) { red[wid] = dxacc; red[4 + wid] = dyacc; }
        __syncthreads();
        if (t == 0) {
            ws[NCC_BLOCKS + sb] = red[0] + red[1] + red[2] + red[3];
            ws[NCC_BLOCKS + SM_BLOCKS + sb] = red[4] + red[5] + red[6] + red[7];
        }
    }
}

__global__ __launch_bounds__(256) void finalize_kernel(const float* __restrict__ ws,
                                                       float* __restrict__ out) {
    __shared__ double sd[256];
    __shared__ double res[3];
    const int t = threadIdx.x;
    double cc = 0.0, dx = 0.0, dy = 0.0;
    for (int i = t; i < NCC_BLOCKS; i += 256) cc += (double)ws[i];
    for (int i = t; i < SM_BLOCKS; i += 256) dx += (double)ws[NCC_BLOCKS + i];
    for (int i = t; i < SM_BLOCKS; i += 256) dy += (double)ws[NCC_BLOCKS + SM_BLOCKS + i];

    sd[t] = cc; __syncthreads();
    for (int s = 128; s; s >>= 1) { if (t < s) sd[t] += sd[t + s]; __syncthreads(); }
    if (t == 0) res[0] = sd[0];
    __syncthreads();
    sd[t] = dx; __syncthreads();
    for (int s = 128; s; s >>= 1) { if (t < s) sd[t] += sd[t + s]; __syncthreads(); }
    if (t == 0) res[1] = sd[0];
    __syncthreads();
    sd[t] = dy; __syncthreads();
    for (int s = 128; s; s >>= 1) { if (t < s) sd[t] += sd[t + s]; __syncthreads(); }
    if (t == 0) {
        res[2] = sd[0];
        const double ncc = -(res[0] / ((double)NB * 1.0 * HH * WW));
        const double mdx = res[1] / ((double)NB * 2.0 * HH * (WW - 1));
        const double mdy = res[2] / ((double)NB * 2.0 * (HH - 1) * WW);
        const double smooth = 0.01 * 0.5 * (mdx + mdy);
        out[0] = (float)(ncc + smooth);
        out[1] = (float)ncc;
        out[2] = (float)smooth;
    }
}

extern "C" void kernel_launch(void* const* d_in, const int* in_sizes, int n_in,
                              void* d_out, int out_size, void* d_ws, size_t ws_size,
                              hipStream_t stream) {
    const float* I = (const float*)d_in[0];
    const float* J = (const float*)d_in[1];
    const float* S = (const float*)d_in[2];
    float* ws = (float*)d_ws;
    float* out = (float*)d_out;

    fused_kernel<<<GRID, 256, 0, stream>>>(I, J, S, ws);
    finalize_kernel<<<1, 256, 0, stream>>>(ws, out);
}